// Round 19
// baseline (301.945 us; speedup 1.0000x reference)
//
#include <hip/hip_runtime.h>

#define NNODES 50000
#define NEDGES 200000
#define DD 128
#define LN_EPS 1e-5f
#define NTH 256

typedef __attribute__((ext_vector_type(8))) short bf16x8;
typedef __attribute__((ext_vector_type(4))) float f32x4;
typedef __attribute__((ext_vector_type(16))) float f32x16;

template<int N> struct ic { static constexpr int value = N; };

__device__ __forceinline__ unsigned short bfr(float f) {
    union { float f; unsigned u; } v; v.f = f;
    return (unsigned short)((v.u + 0x7fffu + ((v.u >> 16) & 1u)) >> 16);
}
__device__ __forceinline__ unsigned pk2(float a, float b) {
    return (unsigned)bfr(a) | ((unsigned)bfr(b) << 16);
}
__device__ __forceinline__ void gload_lds16(const void* g, void* l) {
    __builtin_amdgcn_global_load_lds(
        (const __attribute__((address_space(1))) void*)g,
        (__attribute__((address_space(3))) void*)l, 16, 0, 0);
}

// ---------------------------------------------------------------------------
// Fused pre-pass: blocks [0,72)  -> weight image builder (r6-proven layout)
//                 blocks [72, +1024) -> nodef bf16 mirror + receiver histogram
// ---------------------------------------------------------------------------
__global__ __launch_bounds__(NTH)
void prepass(const float* __restrict__ We1, const float* __restrict__ We2,
             const float* __restrict__ We3, const float* __restrict__ Wn1,
             const float* __restrict__ Wn2, const float* __restrict__ Wn3,
             char* __restrict__ img_e, char* __restrict__ img_n,
             const float* __restrict__ nodef, const int* __restrict__ recv,
             uint4* __restrict__ nodb, int* __restrict__ cnt) {
    if (blockIdx.x < 72) {
        int tid = blockIdx.x * NTH + threadIdx.x;
        const float* W; char* dst; int q;
        if      (tid <  6144) { W = We1; dst = img_e;             q = tid;         }
        else if (tid <  8192) { W = We2; dst = img_e + 12 * 8192; q = tid - 6144;  }
        else if (tid < 10240) { W = We3; dst = img_e + 16 * 8192; q = tid - 8192;  }
        else if (tid < 14336) { W = Wn1; dst = img_n;             q = tid - 10240; }
        else if (tid < 16384) { W = Wn2; dst = img_n + 8 * 8192;  q = tid - 14336; }
        else if (tid < 18432) { W = Wn3; dst = img_n + 12 * 8192; q = tid - 16384; }
        else return;
        int c = q >> 9, rem = q & 511;
        int nt = rem >> 7, r2 = rem & 127, n32 = r2 >> 2, ks = r2 & 3;
        int n = nt * 32 + n32;
        int sx = (n32 + (n32 >> 2)) & 3;
        int k0 = c * 32 + ks * 8;
        unsigned short o[8];
        #pragma unroll
        for (int e = 0; e < 8; ++e)
            o[e] = bfr(W[(size_t)(k0 + e) * DD + n]);
        uint4 val;
        val.x = (unsigned)o[0] | ((unsigned)o[1] << 16);
        val.y = (unsigned)o[2] | ((unsigned)o[3] << 16);
        val.z = (unsigned)o[4] | ((unsigned)o[5] << 16);
        val.w = (unsigned)o[6] | ((unsigned)o[7] << 16);
        *(uint4*)(dst + (size_t)c * 8192 + nt * 2048 + n32 * 64 + ((ks ^ sx) << 4)) = val;
    } else {
        const int b = blockIdx.x - 72;
        const int tid0 = b * NTH + threadIdx.x;
        if (tid0 < NEDGES) atomicAdd(&cnt[recv[tid0]], 1);
        const int NG = NNODES * 16;
        for (int g = tid0; g < NG; g += 1024 * NTH) {
            f32x4 a = ((const f32x4*)nodef)[g * 2];
            f32x4 bb = ((const f32x4*)nodef)[g * 2 + 1];
            uint4 o;
            o.x = pk2(a[0], a[1]); o.y = pk2(a[2], a[3]);
            o.z = pk2(bb[0], bb[1]); o.w = pk2(bb[2], bb[3]);
            nodb[g] = o;
        }
    }
}

// ---------------------------------------------------------------------------
// CSR: 2-level scan. cursor doubles as live fill cursor for the edge kernel.
// ---------------------------------------------------------------------------
__global__ __launch_bounds__(NTH)
void csr_scan1(const int* __restrict__ cnt, int* __restrict__ part) {
    __shared__ int red[NTH];
    const int b = blockIdx.x, t = threadIdx.x;
    const int base = b * 196;
    int s = 0;
    for (int i = t; i < 196; i += NTH) {
        int idx = base + i;
        if (idx < NNODES) s += cnt[idx];
    }
    red[t] = s;
    __syncthreads();
    for (int d = NTH / 2; d > 0; d >>= 1) {
        if (t < d) red[t] += red[t + d];
        __syncthreads();
    }
    if (t == 0) part[b] = red[0];
}

__global__ __launch_bounds__(NTH)
void csr_scan2(const int* __restrict__ cnt, const int* __restrict__ part,
               int* __restrict__ off, int* __restrict__ cursor) {
    __shared__ int sp[NTH];
    const int t = threadIdx.x;
    sp[t] = part[t];
    __syncthreads();
    for (int d = 1; d < NTH; d <<= 1) {
        int v = (t >= d) ? sp[t - d] : 0;
        __syncthreads();
        sp[t] += v;
        __syncthreads();
    }
    int run = (t == 0) ? 0 : sp[t - 1];
    const int base = t * 196;
    for (int i = 0; i < 196; ++i) {
        int idx = base + i;
        if (idx < NNODES) { off[idx] = run; cursor[idx] = run; run += cnt[idx]; }
    }
    if (t == NTH - 1) off[NNODES] = NEDGES;
}

// ---------------------------------------------------------------------------
// Aggregate (bf16): ybuf is CSR-ordered -> pure streaming reads.
// ---------------------------------------------------------------------------
__global__ __launch_bounds__(NTH)
void aggregate(const unsigned* __restrict__ ybuf,
               const int* __restrict__ off,
               unsigned* __restrict__ aggb) {
    const int n = blockIdx.x * 4 + (threadIdx.x >> 6);
    const int l = threadIdx.x & 63;
    if (n >= NNODES) return;
    const int j0 = off[n], j1 = off[n + 1];
    float sx = 0.f, sy = 0.f;
    int j = j0;
    for (; j + 4 <= j1; j += 4) {
        unsigned v0 = ybuf[(size_t)j * 64 + l];
        unsigned v1 = ybuf[(size_t)(j + 1) * 64 + l];
        unsigned v2 = ybuf[(size_t)(j + 2) * 64 + l];
        unsigned v3 = ybuf[(size_t)(j + 3) * 64 + l];
        sx += __uint_as_float(v0 << 16) + __uint_as_float(v1 << 16)
            + __uint_as_float(v2 << 16) + __uint_as_float(v3 << 16);
        sy += __uint_as_float(v0 & 0xffff0000u) + __uint_as_float(v1 & 0xffff0000u)
            + __uint_as_float(v2 & 0xffff0000u) + __uint_as_float(v3 & 0xffff0000u);
    }
    for (; j < j1; ++j) {
        unsigned v = ybuf[(size_t)j * 64 + l];
        sx += __uint_as_float(v << 16);
        sy += __uint_as_float(v & 0xffff0000u);
    }
    aggb[(size_t)n * 64 + l] = pk2(sx, sy);
}

// ---------------------------------------------------------------------------
// Fused MLP, 32x32x16 MFMA (r18 structure; NEW: B prefetch lead 2->4 chunks,
// matching the stage lead).  bS ring 6 slots (chunk c%6, exactly 6 live);
// fS 4 slots (chunks 8..11 all live, no reuse).  Iter M issues B(2M+4,2M+5);
// prologue issues B0..B3.  vmcnt tables re-derived from the exact FIFO:
//   edge: 20,24,24,28,24,16,8,8,4,0   node: 20,24,16,12,8,8,4,0
// (compiler-inserted vmem is either drained before the stages (claim/idx
// loads: shfl forces a wait) or newer than the target stage -> waits only
// err strict).  Inline CSR slot-claim: hi==0 lane claims, shfl-broadcast.
// ---------------------------------------------------------------------------
template<int MODE>
__global__ __launch_bounds__(NTH, 2)
void mgn_mfma(const float* __restrict__ nodef, const float* __restrict__ edgef,
              const unsigned short* __restrict__ nodb,
              const int* __restrict__ senders, const int* __restrict__ receivers,
              int* __restrict__ cursor,
              const char* __restrict__ img,
              const float* __restrict__ b1, const float* __restrict__ b2,
              const float* __restrict__ b3,
              const float* __restrict__ gamma, const float* __restrict__ beta,
              const unsigned short* __restrict__ aggb, unsigned* __restrict__ ybuf,
              float* __restrict__ outp)
{
    __shared__ char Wbuf[6 * 8192];   // 6 rotating k32 weight chunks (3 pairs)
    __shared__ char Hb[4 * 8192];     // per-wave 32 rows x 128 k bf16, swizzled

    const int t  = threadIdx.x;
    const int w  = t >> 6;
    const int l  = t & 63;
    const int ln = l & 31;
    const int hi = l >> 5;
    const int row0 = blockIdx.x * 128;
    const int gm = row0 + w * 32 + ln;
    constexpr int NROWS = (MODE == 0) ? NEDGES : NNODES;
    constexpr int NK1   = (MODE == 0) ? 12 : 8;
    constexpr int NCH   = NK1 + 8;
    const int gmc = gm < NROWS ? gm : NROWS - 1;
    const int sxA = (ln + (ln >> 2)) & 3;
    const int sxH = ln & 15;

    int srow = 0, rrow = 0, prow = 0;
    if (MODE == 0) {
        srow = senders[gmc]; rrow = receivers[gmc];
        int pclaim = 0;
        if (hi == 0 && gm < NROWS) pclaim = atomicAdd(&cursor[rrow], 1);
        prow = __shfl(pclaim, ln);   // both halves of row gm share one slot
    }

    const f32x16 fz = {0.f,0.f,0.f,0.f,0.f,0.f,0.f,0.f,
                       0.f,0.f,0.f,0.f,0.f,0.f,0.f,0.f};
    f32x16 acc[4];
    #pragma unroll
    for (int nt = 0; nt < 4; ++nt) acc[nt] = fz;

    bf16x8 bS[6][2];   // bf16 B ring (6 chunk slots, lead-4)
    f32x4  fS[4][4];   // fp32 B ring (edge chunks 8..11, all live)

    auto stageW = [&](int c) {
        const char* src = img + (size_t)c * 8192 + t * 16;
        char* dstl = Wbuf + (c % 6) * 8192 + t * 16;
        gload_lds16(src, dstl);
        gload_lds16(src + 4096, dstl + 4096);
    };

    auto loadBB = [&](auto CC, bf16x8* dst) {
        constexpr int c = decltype(CC)::value;
        const unsigned short* base;
        if constexpr (MODE == 0) {
            base = (c < 4) ? nodb + (size_t)srow * DD : nodb + (size_t)rrow * DD;
        } else {
            base = (c < 4) ? nodb + (size_t)gmc * DD : aggb + (size_t)gmc * DD;
        }
        const char* p = (const char*)base + (c & 3) * 64 + hi * 16;
        dst[0] = *(const bf16x8*)p;
        dst[1] = *(const bf16x8*)(p + 32);
    };

    auto loadBF = [&](auto CC, f32x4* dst) {
        constexpr int c = decltype(CC)::value;
        const float* p = edgef + (size_t)gmc * DD + (c & 3) * 32 + hi * 8;
        dst[0] = *(const f32x4*)p;
        dst[1] = *(const f32x4*)(p + 4);
        dst[2] = *(const f32x4*)(p + 16);
        dst[3] = *(const f32x4*)(p + 20);
    };

    auto cvtB = [&](const f32x4* br) {
        union { unsigned u[4]; bf16x8 v; } r;
        r.u[0] = pk2(br[0][0], br[0][1]);
        r.u[1] = pk2(br[0][2], br[0][3]);
        r.u[2] = pk2(br[1][0], br[1][1]);
        r.u[3] = pk2(br[1][2], br[1][3]);
        return r.v;
    };

    auto loadBH = [&](int ks, int kh) {
        const char* p = Hb + w * 8192 + ln * 256
                      + (((ks * 4 + kh * 2 + hi) ^ sxH) << 4);
        return *(const bf16x8*)p;
    };

    auto getB = [&](auto CC, int kh) -> bf16x8 {
        constexpr int c = decltype(CC)::value;
        if constexpr (c >= NK1) {
            return loadBH((c - NK1) & 3, kh);
        } else if constexpr (MODE == 0 && c >= 8) {
            return cvtB(&fS[c & 3][kh * 2]);
        } else {
            return bS[c % 6][kh];
        }
    };

    auto compute = [&](auto CC) {
        constexpr int c = decltype(CC)::value;
        const char* bp = Wbuf + (c % 6) * 8192 + ln * 64;
        #pragma unroll
        for (int kh = 0; kh < 2; ++kh) {
            bf16x8 b = getB(CC, kh);
            #pragma unroll
            for (int nt = 0; nt < 4; ++nt) {
                bf16x8 a = *(const bf16x8*)(bp + nt * 2048
                            + (((kh * 2 + hi) ^ sxA) << 4));
                acc[nt] = __builtin_amdgcn_mfma_f32_32x32x16_bf16(a, b, acc[nt], 0, 0, 0);
            }
        }
    };

    auto epiH = [&](const float* bias) {
        #pragma unroll
        for (int nt = 0; nt < 4; ++nt) {
            #pragma unroll
            for (int rq = 0; rq < 4; ++rq) {
                f32x4 bv = *(const f32x4*)(bias + nt * 32 + rq * 8 + hi * 4);
                unsigned short h[4];
                #pragma unroll
                for (int j = 0; j < 4; ++j)
                    h[j] = bfr(fmaxf(acc[nt][rq * 4 + j] + bv[j], 0.f));
                char* p = Hb + w * 8192 + ln * 256
                        + (((nt * 4 + rq) ^ sxH) << 4) + hi * 8;
                unsigned lo = (unsigned)h[0] | ((unsigned)h[1] << 16);
                unsigned hx = (unsigned)h[2] | ((unsigned)h[3] << 16);
                *(unsigned long long*)p =
                    (unsigned long long)lo | ((unsigned long long)hx << 32);
            }
            acc[nt] = fz;
        }
    };

    auto loadB = [&](auto CC) {
        constexpr int c = decltype(CC)::value;
        if constexpr (c < NK1) {
            if constexpr (MODE == 0 && c >= 8) loadBF(CC, fS[c & 3]);
            else                               loadBB(CC, bS[c % 6]);
        }
    };

// Macro-iter M: chunks (2M, 2M+1). barrier -> stage pair (2M+4,2M+5) ->
// B pair (2M+4,2M+5) [lead-4] -> counted vmcnt -> compute pair.
#define PITER2(M, VM)                                                         \
    {                                                                         \
        __builtin_amdgcn_s_barrier();                                         \
        __builtin_amdgcn_sched_barrier(0);                                    \
        if constexpr (2*(M) + 4 < NCH) stageW(2*(M) + 4);                     \
        if constexpr (2*(M) + 5 < NCH) stageW(2*(M) + 5);                     \
        __builtin_amdgcn_sched_barrier(0);                                    \
        loadB(ic<2*(M) + 4>{});                                               \
        loadB(ic<2*(M) + 5>{});                                               \
        __builtin_amdgcn_sched_barrier(0);                                    \
        asm volatile("s_waitcnt vmcnt(" #VM ")" ::: "memory");                \
        __builtin_amdgcn_sched_barrier(0);                                    \
        compute(ic<2*(M)>{});                                                 \
        compute(ic<2*(M) + 1>{});                                             \
    }

    // prologue: S0..S3 then B0..B3 (order pinned; claim already drained)
    stageW(0);
    __builtin_amdgcn_sched_barrier(0);
    stageW(1);
    __builtin_amdgcn_sched_barrier(0);
    stageW(2);
    __builtin_amdgcn_sched_barrier(0);
    stageW(3);
    __builtin_amdgcn_sched_barrier(0);
    loadB(ic<0>{});
    loadB(ic<1>{});
    loadB(ic<2>{});
    loadB(ic<3>{});
    __builtin_amdgcn_sched_barrier(0);

    if constexpr (MODE == 0) {
        PITER2(0, 20)  PITER2(1, 24)  PITER2(2, 24)  PITER2(3, 28)
        PITER2(4, 24)  PITER2(5, 16)
        epiH(b1);
        PITER2(6, 8)   PITER2(7, 8)
        epiH(b2);
        PITER2(8, 4)   PITER2(9, 0)
    } else {
        PITER2(0, 20)  PITER2(1, 24)  PITER2(2, 16)  PITER2(3, 12)
        epiH(b1);
        PITER2(4, 8)   PITER2(5, 8)
        epiH(b2);
        PITER2(6, 4)   PITER2(7, 0)
    }
#undef PITER2

    // ================= bias3 + LayerNorm + residual (+ ybuf) =================
    float vsum = 0.f, vsq = 0.f;
    #pragma unroll
    for (int nt = 0; nt < 4; ++nt) {
        #pragma unroll
        for (int rq = 0; rq < 4; ++rq) {
            f32x4 bv = *(const f32x4*)(b3 + nt * 32 + rq * 8 + hi * 4);
            #pragma unroll
            for (int j = 0; j < 4; ++j) {
                float v = acc[nt][rq * 4 + j] + bv[j];
                acc[nt][rq * 4 + j] = v;
                vsum += v; vsq += v * v;
            }
        }
    }
    vsum += __shfl_xor(vsum, 32);
    vsq  += __shfl_xor(vsq, 32);
    const float mu = vsum * (1.f / DD);
    const float rs = rsqrtf(vsq * (1.f / DD) - mu * mu + LN_EPS);

    if (gm < NROWS) {
        const float* resid = ((MODE == 0) ? edgef : nodef) + (size_t)gm * DD;
        #pragma unroll
        for (int nt = 0; nt < 4; ++nt) {
            #pragma unroll
            for (int rq = 0; rq < 4; ++rq) {
                const int n0 = nt * 32 + rq * 8 + hi * 4;
                f32x4 gv = *(const f32x4*)(gamma + n0);
                f32x4 bv = *(const f32x4*)(beta + n0);
                f32x4 rv = *(const f32x4*)(resid + n0);
                float y[4];
                f32x4 o;
                #pragma unroll
                for (int j = 0; j < 4; ++j) {
                    y[j] = (acc[nt][rq * 4 + j] - mu) * rs * gv[j] + bv[j];
                    o[j] = y[j] + rv[j];
                }
                *(f32x4*)(outp + (size_t)gm * DD + n0) = o;
                if (MODE == 0) {
                    unsigned long long pkd =
                        (unsigned long long)pk2(y[0], y[1])
                      | ((unsigned long long)pk2(y[2], y[3]) << 32);
                    *(unsigned long long*)((char*)ybuf + (size_t)prow * 256 + n0 * 2) = pkd;
                }
            }
        }
    }
}

extern "C" void kernel_launch(void* const* d_in, const int* in_sizes, int n_in,
                              void* d_out, int out_size, void* d_ws, size_t ws_size,
                              hipStream_t stream) {
    const float* nodef = (const float*)d_in[0];
    const float* edgef = (const float*)d_in[1];
    const int* senders   = (const int*)d_in[2];
    const int* receivers = (const int*)d_in[3];
    const float* We1 = (const float*)d_in[4],  *be1 = (const float*)d_in[5];
    const float* We2 = (const float*)d_in[6],  *be2 = (const float*)d_in[7];
    const float* We3 = (const float*)d_in[8],  *be3 = (const float*)d_in[9];
    const float* ge  = (const float*)d_in[10], *bege = (const float*)d_in[11];
    const float* Wn1 = (const float*)d_in[12], *bn1 = (const float*)d_in[13];
    const float* Wn2 = (const float*)d_in[14], *bn2 = (const float*)d_in[15];
    const float* Wn3 = (const float*)d_in[16], *bn3 = (const float*)d_in[17];
    const float* gn  = (const float*)d_in[18], *begn = (const float*)d_in[19];

    float* out_node = (float*)d_out;
    float* out_edge = (float*)d_out + (size_t)NNODES * DD;

    char* ws = (char*)d_ws;
    size_t o = 0;
    unsigned short* aggb = (unsigned short*)(ws + o); o += (size_t)NNODES * 256;
    unsigned* ybuf = (unsigned*)(ws + o);             o += (size_t)NEDGES * 256;
    unsigned short* nodb = (unsigned short*)(ws + o); o += (size_t)NNODES * 256;
    char* img_e = ws + o;           o += 20 * 8192;
    char* img_n = ws + o;           o += 16 * 8192;
    int* cnt    = (int*)(ws + o);   o += NNODES * 4;
    int* cursor = (int*)(ws + o);   o += NNODES * 4;
    int* off    = (int*)(ws + o);   o += (NNODES + 4) * 4;
    int* part   = (int*)(ws + o);   o += NTH * 4;

    hipMemsetAsync(cnt, 0, NNODES * 4, stream);
    prepass<<<72 + 1024, NTH, 0, stream>>>(We1, We2, We3, Wn1, Wn2, Wn3,
                                           img_e, img_n,
                                           nodef, receivers, (uint4*)nodb, cnt);
    csr_scan1<<<NTH, NTH, 0, stream>>>(cnt, part);
    csr_scan2<<<1, NTH, 0, stream>>>(cnt, part, off, cursor);

    mgn_mfma<0><<<dim3((NEDGES + 127) / 128), dim3(NTH), 0, stream>>>(
        nodef, edgef, nodb, senders, receivers, cursor, img_e,
        be1, be2, be3, ge, bege, aggb, ybuf, out_edge);

    aggregate<<<(NNODES + 3) / 4, NTH, 0, stream>>>(ybuf, off, (unsigned*)aggb);

    mgn_mfma<1><<<dim3((NNODES + 127) / 128), dim3(NTH), 0, stream>>>(
        nodef, edgef, nodb, senders, receivers, cursor, img_n,
        bn1, bn2, bn3, gn, begn, aggb, ybuf, out_node);
}